// Round 11
// baseline (470.920 us; speedup 1.0000x reference)
//
#include <hip/hip_runtime.h>

#define N_NODES 50000
#define N_EDGES 800000
#define N_RELS  32
#define D       64
#define NBKT    196                         // ceil(50000/256) dst buckets
#define EPB     2048                        // edges per block in kA/kC
#define NEBLK   ((N_EDGES + EPB - 1) / EPB) // 391
#define CAP     4096                        // per-quarter edge cap (mean ~1020+pad)
#define MAXCH   (CAP / 16)                  // 256 chunks
#define FEATH_BLKS ((N_NODES * D / 8 + 255) / 256)   // 1563

typedef _Float16 half8 __attribute__((ext_vector_type(8)));
typedef float    f32x4 __attribute__((ext_vector_type(4)));

// ---------------- workspace layout (bytes) ----------------
#define OFF_BKTHIST 0u          // 196 int (block 0 of kPre zeroes [0,1024))
#define OFF_BKTCUR  1024u       // 196 int
#define OFF_BKTOFF  2048u       // 197 int
#define OFF_BUCK    4096u       // 800000 int: src | dstlocal<<16 | rel<<24
#define OFF_WT      3204096u    // 32*64*64 fp16 (W^T per rel, [o][k])
#define OFF_FEATH   3466240u    // 50000*64 fp16
#define WS_NEED_B   3466240u
#define WS_NEED_H   9866240u

// ---------------- fallback: atomic scatter path ----------------
__global__ __launch_bounds__(256) void rgcn_edge_atomic(
    const float* __restrict__ feat, const float* __restrict__ weight,
    const int* __restrict__ src, const int* __restrict__ dst,
    const int* __restrict__ et, float* __restrict__ out, int nquads)
{
    const int tid  = blockIdx.x * blockDim.x + threadIdx.x;
    const int wave = tid >> 6, lane = tid & 63;
    const int grp = lane >> 4, lg = lane & 15;
    const int wave_stride = (gridDim.x * blockDim.x) >> 6;
    for (int q = wave; q < nquads; q += wave_stride) {
        const int e = q * 4 + grp;
        const int s = src[e], d = dst[e], r = et[e];
        const float* w = weight + (size_t)r * D * D + lg * 4;
        float ax = 0.f, ay = 0.f, az = 0.f, aw = 0.f;
        #pragma unroll
        for (int i4 = 0; i4 < D / 4; ++i4) {
            const float4 f  = *reinterpret_cast<const float4*>(feat + (size_t)s * D + i4 * 4);
            const float4 w0 = *reinterpret_cast<const float4*>(w + (i4 * 4 + 0) * D);
            const float4 w1 = *reinterpret_cast<const float4*>(w + (i4 * 4 + 1) * D);
            const float4 w2 = *reinterpret_cast<const float4*>(w + (i4 * 4 + 2) * D);
            const float4 w3 = *reinterpret_cast<const float4*>(w + (i4 * 4 + 3) * D);
            ax += f.x*w0.x; ay += f.x*w0.y; az += f.x*w0.z; aw += f.x*w0.w;
            ax += f.y*w1.x; ay += f.y*w1.y; az += f.y*w1.z; aw += f.y*w1.w;
            ax += f.z*w2.x; ay += f.z*w2.y; az += f.z*w2.z; aw += f.z*w2.w;
            ax += f.w*w3.x; ay += f.w*w3.y; az += f.w*w3.z; aw += f.w*w3.w;
        }
        float* orow = out + (size_t)d * D + lg * 4;
        atomicAdd(orow + 0, ax); atomicAdd(orow + 1, ay);
        atomicAdd(orow + 2, az); atomicAdd(orow + 3, aw);
    }
}

// ---------------- kPre: zero hists + W->W^T fp16 + feat->fp16 ----------------
__global__ __launch_bounds__(256) void kPre(const float* __restrict__ w,
                                            _Float16* __restrict__ wT,
                                            const float* __restrict__ feat,
                                            _Float16* __restrict__ featH,
                                            int* __restrict__ histzero)
{
    const int t = threadIdx.x;
    if (blockIdx.x < N_RELS) {
        if (blockIdx.x == 0) histzero[t] = 0;     // 256 ints: bkthist + pad
        const int r = blockIdx.x;
        #pragma unroll
        for (int i = 0; i < 16; ++i) {
            int oidx = i * 256 + t;               // o*64+k
            int o = oidx >> 6, k = oidx & 63;
            wT[(size_t)r * 4096 + oidx] = (_Float16)w[(size_t)r * 4096 + k * 64 + o];
        }
    } else {
        const int base = ((blockIdx.x - N_RELS) * 256 + t) * 8;
        if (base >= N_NODES * D) return;
        float4 f0 = *reinterpret_cast<const float4*>(feat + base);
        float4 f1 = *reinterpret_cast<const float4*>(feat + base + 4);
        half8 h;
        h[0]=(_Float16)f0.x; h[1]=(_Float16)f0.y; h[2]=(_Float16)f0.z; h[3]=(_Float16)f0.w;
        h[4]=(_Float16)f1.x; h[5]=(_Float16)f1.y; h[6]=(_Float16)f1.z; h[7]=(_Float16)f1.w;
        *reinterpret_cast<half8*>(featH + base) = h;
    }
}

// ---------------- kA: LDS-aggregated dst-bucket histogram ----------------
__global__ __launch_bounds__(256) void kA_hist(const int* __restrict__ dst,
                                               int* __restrict__ bkthist)
{
    __shared__ int lb[NBKT];
    const int t = threadIdx.x;
    if (t < NBKT) lb[t] = 0;
    __syncthreads();
    const int base = blockIdx.x * EPB + t * 8;
    #pragma unroll
    for (int i = 0; i < 8; ++i) {
        int e = base + i;
        if (e < N_EDGES) atomicAdd(&lb[dst[e] >> 8], 1);
    }
    __syncthreads();
    if (t < NBKT && lb[t]) atomicAdd(&bkthist[t], lb[t]);
}

// ---------------- kB: scan bucket counts -> bktoff/bktcur ----------------
__global__ __launch_bounds__(256) void kB_scan(const int* __restrict__ bkthist,
                                               int* __restrict__ bktoff,
                                               int* __restrict__ bktcur)
{
    __shared__ int s[256];
    const int t = threadIdx.x;
    int v = (t < NBKT) ? bkthist[t] : 0;
    s[t] = v; __syncthreads();
    #pragma unroll
    for (int off = 1; off < 256; off <<= 1) {
        int u = (t >= off) ? s[t - off] : 0;
        __syncthreads(); s[t] += u; __syncthreads();
    }
    if (t < NBKT) { int ex = s[t] - v; bktoff[t] = ex; bktcur[t] = ex; }
    if (t == NBKT - 1) bktoff[NBKT] = s[t];
}

// ---------------- kC: scatter edges into dst buckets (packed) ----------------
__global__ __launch_bounds__(256) void kC_scatter(const int* __restrict__ src,
                                                  const int* __restrict__ dst,
                                                  const int* __restrict__ et,
                                                  int* __restrict__ bktcur,
                                                  int* __restrict__ bucketed)
{
    __shared__ int lb[NBKT], lbase[NBKT];
    const int t = threadIdx.x;
    if (t < NBKT) lb[t] = 0;
    __syncthreads();
    const int base = blockIdx.x * EPB + t * 8;
    int b_[8], pk[8], sl[8];
    #pragma unroll
    for (int i = 0; i < 8; ++i) {
        int e = base + i;
        if (e < N_EDGES) {
            int d = dst[e];
            b_[i] = d >> 8;
            pk[i] = src[e] | ((d & 255) << 16) | (et[e] << 24);
            sl[i] = atomicAdd(&lb[b_[i]], 1);
        }
    }
    __syncthreads();
    if (t < NBKT && lb[t]) lbase[t] = atomicAdd(&bktcur[t], lb[t]);
    __syncthreads();
    #pragma unroll
    for (int i = 0; i < 8; ++i) {
        int e = base + i;
        if (e < N_EDGES)
            bucketed[lbase[b_[i]] + sl[i]] = pk[i];
    }
}

// ---------------- kE: fused per-dst-tile local-rel-sort + MFMA + reduce ------
// Block = (bucket, quarter): 64 dst nodes. LDS: edata 16KB + oacc 17.7KB.
// Per 16-edge chunk (rel-uniform): A gathered direct from featH (lane row=l&15,
// k=(l>>4)*8+ks*32 — layout verified by k4), B direct from L2-hot wT with a
// register cache keyed on rel, 8 MFMAs, D scattered via LDS f32 atomicAdd.
template <bool USE_H>
__global__ __launch_bounds__(256) void kE_fused(const float* __restrict__ feat,
                                                const _Float16* __restrict__ featH,
                                                const _Float16* __restrict__ wT,
                                                const int* __restrict__ bucketed,
                                                const int* __restrict__ bktoff,
                                                float* __restrict__ out)
{
    __shared__ int   edata[CAP];          // src | (tile-local dl)<<16 ; dl=64 dummy
    __shared__ float oacc[65 * 68];       // 64 nodes + trash row; stride 68 (banks)
    __shared__ int   hist[N_RELS], poff[N_RELS], cursor[N_RELS], sS[N_RELS];
    __shared__ int   chrel[MAXCH];
    __shared__ int   nchunk_s;

    const int t = threadIdx.x;
    const int bkt = blockIdx.x >> 2, q = blockIdx.x & 3;
    const int lo = bktoff[bkt], hi = bktoff[bkt + 1];

    if (t < N_RELS) hist[t] = 0;
    for (int i = t; i < 65 * 68; i += 256) oacc[i] = 0.f;
    __syncthreads();

    // pass 1: count my quarter's edges per rel
    for (int p = lo + t; p < hi; p += 256) {
        int v = bucketed[p];
        if (((v >> 22) & 3) == q)
            atomicAdd(&hist[(v >> 24) & 31], 1);
    }
    __syncthreads();

    // padded (16-multiple) exclusive scan over 32 rels
    int cnt = 0, pc = 0;
    if (t < N_RELS) { cnt = hist[t]; pc = (cnt + 15) & ~15; sS[t] = pc; }
    __syncthreads();
    #pragma unroll
    for (int off = 1; off < N_RELS; off <<= 1) {
        int u = (t >= off && t < N_RELS) ? sS[t - off] : 0;
        __syncthreads();
        if (t < N_RELS) sS[t] += u;
        __syncthreads();
    }
    if (t < N_RELS) {
        int ex = min(sS[t] - pc, CAP);
        poff[t] = ex; cursor[t] = ex;
        int e1 = min(sS[t], CAP);
        for (int p = min(ex + cnt, CAP); p < e1; ++p) edata[p] = (64 << 16); // pad
        for (int c = ex >> 4; c < (e1 >> 4); ++c) chrel[c] = t;
    }
    if (t == N_RELS - 1) nchunk_s = min(sS[t], CAP) >> 4;
    __syncthreads();

    // pass 2: place (rel-sorted, tile-local dl in bits 16..22)
    for (int p = lo + t; p < hi; p += 256) {
        int v = bucketed[p];
        if (((v >> 22) & 3) == q) {
            int pos = atomicAdd(&cursor[(v >> 24) & 31], 1);
            if (pos < CAP)
                edata[pos] = (v & 0xFFFF) | (((v >> 16) & 63) << 16);
        }
    }
    __syncthreads();

    // compute: contiguous chunk range per wave, register-cached B per rel
    const int wid = t >> 6, l = t & 63;
    const int l15 = l & 15, lk = l >> 4;
    const int nch = nchunk_s;
    const int c0 = (wid * nch) >> 2, c1 = ((wid + 1) * nch) >> 2;

    int rcur = -1;
    half8 bfr[4][2];
    for (int c = c0; c < c1; ++c) {
        const int cb = c << 4;
        const int r = chrel[c];
        if (r != rcur) {
            rcur = r;
            const _Float16* wr = wT + ((size_t)r << 12) + l15 * 64 + lk * 8;
            #pragma unroll
            for (int ct = 0; ct < 4; ++ct) {
                bfr[ct][0] = *reinterpret_cast<const half8*>(wr + ct * 1024);
                bfr[ct][1] = *reinterpret_cast<const half8*>(wr + ct * 1024 + 32);
            }
        }
        const int va = edata[cb + l15];
        half8 af0, af1;
        if (USE_H) {
            const _Float16* ar = featH + ((size_t)(va & 0xFFFF) << 6) + lk * 8;
            af0 = *reinterpret_cast<const half8*>(ar);
            af1 = *reinterpret_cast<const half8*>(ar + 32);
        } else {
            const float* ar = feat + ((size_t)(va & 0xFFFF) << 6) + lk * 8;
            float4 a0 = *reinterpret_cast<const float4*>(ar);
            float4 a1 = *reinterpret_cast<const float4*>(ar + 4);
            float4 a2 = *reinterpret_cast<const float4*>(ar + 32);
            float4 a3 = *reinterpret_cast<const float4*>(ar + 36);
            af0[0]=(_Float16)a0.x; af0[1]=(_Float16)a0.y; af0[2]=(_Float16)a0.z; af0[3]=(_Float16)a0.w;
            af0[4]=(_Float16)a1.x; af0[5]=(_Float16)a1.y; af0[6]=(_Float16)a1.z; af0[7]=(_Float16)a1.w;
            af1[0]=(_Float16)a2.x; af1[1]=(_Float16)a2.y; af1[2]=(_Float16)a2.z; af1[3]=(_Float16)a2.w;
            af1[4]=(_Float16)a3.x; af1[5]=(_Float16)a3.y; af1[6]=(_Float16)a3.z; af1[7]=(_Float16)a3.w;
        }
        f32x4 acc[4];
        #pragma unroll
        for (int ct = 0; ct < 4; ++ct) {
            f32x4 z = {0.f, 0.f, 0.f, 0.f};
            z = __builtin_amdgcn_mfma_f32_16x16x32_f16(af0, bfr[ct][0], z, 0, 0, 0);
            z = __builtin_amdgcn_mfma_f32_16x16x32_f16(af1, bfr[ct][1], z, 0, 0, 0);
            acc[ct] = z;
        }
        // D: lane holds rows lk*4+reg, col ct*16+l15 -> LDS f32 atomic accumulate
        #pragma unroll
        for (int reg = 0; reg < 4; ++reg) {
            int dl = edata[cb + lk * 4 + reg] >> 16;     // 0..64 (64 = trash)
            #pragma unroll
            for (int ct = 0; ct < 4; ++ct)
                atomicAdd(&oacc[dl * 68 + ct * 16 + l15], acc[ct][reg]);
        }
    }
    __syncthreads();

    // write 64 nodes x 64 cols, coalesced
    {
        const int row = t >> 2, cseg = (t & 3) * 16;
        const int n = bkt * 256 + q * 64 + row;
        if (n < N_NODES) {
            float* op = out + ((size_t)n << 6) + cseg;
            #pragma unroll
            for (int j = 0; j < 4; ++j)
                *reinterpret_cast<f32x4*>(op + j * 4) =
                    *reinterpret_cast<const f32x4*>(&oacc[row * 68 + cseg + j * 4]);
        }
    }
}

extern "C" void kernel_launch(void* const* d_in, const int* in_sizes, int n_in,
                              void* d_out, int out_size, void* d_ws, size_t ws_size,
                              hipStream_t stream) {
    const float* feat   = (const float*)d_in[0];
    const float* weight = (const float*)d_in[1];
    const int*   src    = (const int*)d_in[2];
    const int*   dst    = (const int*)d_in[3];
    const int*   et     = (const int*)d_in[4];
    float*       out    = (float*)d_out;

    if (ws_size < (size_t)WS_NEED_B) {
        hipMemsetAsync(d_out, 0, (size_t)out_size * sizeof(float), stream);
        hipLaunchKernelGGL(rgcn_edge_atomic, dim3(4096), dim3(256), 0, stream,
                           feat, weight, src, dst, et, out, N_EDGES / 4);
        return;
    }
    const bool use_h = (ws_size >= (size_t)WS_NEED_H);

    char* ws = (char*)d_ws;
    int*       bkthist  = (int*)(ws + OFF_BKTHIST);
    int*       bktcur   = (int*)(ws + OFF_BKTCUR);
    int*       bktoff   = (int*)(ws + OFF_BKTOFF);
    int*       bucketed = (int*)(ws + OFF_BUCK);
    _Float16*  wT       = (_Float16*)(ws + OFF_WT);
    _Float16*  featH    = (_Float16*)(ws + OFF_FEATH);

    const int pre_blocks = N_RELS + (use_h ? FEATH_BLKS : 0);
    hipLaunchKernelGGL(kPre,       dim3(pre_blocks), dim3(256), 0, stream,
                       weight, wT, feat, featH, (int*)ws);
    hipLaunchKernelGGL(kA_hist,    dim3(NEBLK), dim3(256), 0, stream, dst, bkthist);
    hipLaunchKernelGGL(kB_scan,    dim3(1),     dim3(256), 0, stream, bkthist, bktoff, bktcur);
    hipLaunchKernelGGL(kC_scatter, dim3(NEBLK), dim3(256), 0, stream, src, dst, et, bktcur, bucketed);
    if (use_h)
        hipLaunchKernelGGL((kE_fused<true>),  dim3(NBKT * 4), dim3(256), 0, stream,
                           feat, featH, wT, bucketed, bktoff, out);
    else
        hipLaunchKernelGGL((kE_fused<false>), dim3(NBKT * 4), dim3(256), 0, stream,
                           feat, featH, wT, bucketed, bktoff, out);
}

// Round 12
// 110.683 us; speedup vs baseline: 4.2547x; 4.2547x over previous
//
#include <hip/hip_runtime.h>
#include <hip/hip_bf16.h>

#define N_NODES 50000
#define N_EDGES 800000
#define N_RELS  32
#define D       64
#define TILE_M  128
#define NBKT    196                         // ceil(50000/256)
#define EPB     2048                        // edges per block in kA/kC
#define NEBLK   ((N_EDGES + EPB - 1) / EPB) // 391

typedef _Float16 half8 __attribute__((ext_vector_type(8)));
typedef float    f32x4 __attribute__((ext_vector_type(4)));

// ---------------- workspace layout (bytes) ----------------
#define OFF_RELHIST 0u          // 32 int   (zeroed by kPre block 0)
#define OFF_BKTHIST 128u        // 196 int
#define OFF_RELCUR  1024u       // 32 int
#define OFF_BKTCUR  1152u       // 196 int
#define OFF_ROFF    1936u       // 33 int
#define OFF_TB      2080u       // 33 int
#define OFF_BKTOFF  2224u       // 197 int
#define OFF_DSTOFF  3072u       // 50001 int
#define OFF_RELSRC  203776u     // 800000 int
#define OFF_J2POS   3403776u    // 800000 int (edge j -> dst-CSR position)
#define OFF_WT      6603776u    // 32*64*64 fp16
#define OFF_FEATH   6865920u    // 50000*64 fp16 (full layout only)
#define OFF_Y_FULL  13265920u   // 800000*64 fp16, dst-ordered
#define OFF_Y_BASE  6865920u    // Y location when featH doesn't fit
#define WS_FULL     115665920u
#define WS_BASE     109265920u

// ---------------- fallback: atomic scatter path ----------------
__global__ __launch_bounds__(256) void rgcn_edge_atomic(
    const float* __restrict__ feat, const float* __restrict__ weight,
    const int* __restrict__ src, const int* __restrict__ dst,
    const int* __restrict__ et, float* __restrict__ out, int nquads)
{
    const int tid  = blockIdx.x * blockDim.x + threadIdx.x;
    const int wave = tid >> 6, lane = tid & 63;
    const int grp = lane >> 4, lg = lane & 15;
    const int wave_stride = (gridDim.x * blockDim.x) >> 6;
    for (int q = wave; q < nquads; q += wave_stride) {
        const int e = q * 4 + grp;
        const int s = src[e], d = dst[e], r = et[e];
        const float* w = weight + (size_t)r * D * D + lg * 4;
        float ax = 0.f, ay = 0.f, az = 0.f, aw = 0.f;
        #pragma unroll
        for (int i4 = 0; i4 < D / 4; ++i4) {
            const float4 f  = *reinterpret_cast<const float4*>(feat + (size_t)s * D + i4 * 4);
            const float4 w0 = *reinterpret_cast<const float4*>(w + (i4 * 4 + 0) * D);
            const float4 w1 = *reinterpret_cast<const float4*>(w + (i4 * 4 + 1) * D);
            const float4 w2 = *reinterpret_cast<const float4*>(w + (i4 * 4 + 2) * D);
            const float4 w3 = *reinterpret_cast<const float4*>(w + (i4 * 4 + 3) * D);
            ax += f.x*w0.x; ay += f.x*w0.y; az += f.x*w0.z; aw += f.x*w0.w;
            ax += f.y*w1.x; ay += f.y*w1.y; az += f.y*w1.z; aw += f.y*w1.w;
            ax += f.z*w2.x; ay += f.z*w2.y; az += f.z*w2.z; aw += f.z*w2.w;
            ax += f.w*w3.x; ay += f.w*w3.y; az += f.w*w3.z; aw += f.w*w3.w;
        }
        float* orow = out + (size_t)d * D + lg * 4;
        atomicAdd(orow + 0, ax); atomicAdd(orow + 1, ay);
        atomicAdd(orow + 2, az); atomicAdd(orow + 3, aw);
    }
}

// ---------------- kPre: zero hists + W->W^T fp16 + feat->fp16 (fused) -------
__global__ __launch_bounds__(256) void kPre(const float* __restrict__ w,
                                            _Float16* __restrict__ wT,
                                            const float* __restrict__ feat,
                                            _Float16* __restrict__ featH,
                                            int* __restrict__ histzero)
{
    const int t = threadIdx.x;
    if (blockIdx.x < N_RELS) {
        if (blockIdx.x == 0 && t < 228)     // relhist(32) + bkthist(196)
            histzero[t] = 0;
        const int r = blockIdx.x;
        #pragma unroll
        for (int i = 0; i < 16; ++i) {
            int oidx = i * 256 + t;
            int o = oidx >> 6, k = oidx & 63;
            wT[(size_t)r * 4096 + oidx] = (_Float16)w[(size_t)r * 4096 + k * 64 + o];
        }
    } else {
        const int base = ((blockIdx.x - N_RELS) * 256 + t) * 8;
        if (base >= N_NODES * D) return;
        float4 f0 = *reinterpret_cast<const float4*>(feat + base);
        float4 f1 = *reinterpret_cast<const float4*>(feat + base + 4);
        half8 h;
        h[0]=(_Float16)f0.x; h[1]=(_Float16)f0.y; h[2]=(_Float16)f0.z; h[3]=(_Float16)f0.w;
        h[4]=(_Float16)f1.x; h[5]=(_Float16)f1.y; h[6]=(_Float16)f1.z; h[7]=(_Float16)f1.w;
        *reinterpret_cast<half8*>(featH + base) = h;
    }
}

// ---------------- kA: LDS-aggregated rel + bucket histograms ----------------
__global__ __launch_bounds__(256) void kA_hist(const int* __restrict__ et,
                                               const int* __restrict__ dst,
                                               int* __restrict__ relhist,
                                               int* __restrict__ bkthist)
{
    __shared__ int lh[N_RELS];
    __shared__ int lb[NBKT];
    const int t = threadIdx.x;
    if (t < N_RELS) lh[t] = 0;
    if (t < NBKT)   lb[t] = 0;
    __syncthreads();
    const int base = blockIdx.x * EPB + t * 8;
    #pragma unroll
    for (int i = 0; i < 8; ++i) {
        int e = base + i;
        if (e < N_EDGES) {
            atomicAdd(&lh[et[e]], 1);
            atomicAdd(&lb[dst[e] >> 8], 1);
        }
    }
    __syncthreads();
    if (t < N_RELS && lh[t]) atomicAdd(&relhist[t], lh[t]);
    if (t < NBKT   && lb[t]) atomicAdd(&bkthist[t], lb[t]);
}

// ---------------- kB: parallel scans (rel offsets, tile table, bucket offs) -
__global__ __launch_bounds__(256) void kB_scan(const int* __restrict__ relhist,
                                               const int* __restrict__ bkthist,
                                               int* __restrict__ roff,
                                               int* __restrict__ relcur,
                                               int* __restrict__ tb,
                                               int* __restrict__ bktoff,
                                               int* __restrict__ bktcur,
                                               int* __restrict__ dst_off)
{
    __shared__ int s[256];
    const int t = threadIdx.x;
    int v = (t < N_RELS) ? relhist[t] : 0;
    s[t] = v; __syncthreads();
    #pragma unroll
    for (int off = 1; off < 32; off <<= 1) {
        int u = (t >= off && t < N_RELS) ? s[t - off] : 0;
        __syncthreads(); s[t] += u; __syncthreads();
    }
    if (t < N_RELS) { int ex = s[t] - v; roff[t] = ex; relcur[t] = ex; }
    if (t == N_RELS - 1) roff[N_RELS] = s[t];
    __syncthreads();
    int w = (v + TILE_M - 1) / TILE_M;
    s[t] = (t < N_RELS) ? w : 0; __syncthreads();
    #pragma unroll
    for (int off = 1; off < 32; off <<= 1) {
        int u = (t >= off && t < N_RELS) ? s[t - off] : 0;
        __syncthreads(); s[t] += u; __syncthreads();
    }
    if (t < N_RELS) tb[t] = s[t] - w;
    if (t == N_RELS - 1) tb[N_RELS] = s[t];
    __syncthreads();
    int v2 = (t < NBKT) ? bkthist[t] : 0;
    s[t] = v2; __syncthreads();
    #pragma unroll
    for (int off = 1; off < 256; off <<= 1) {
        int u = (t >= off) ? s[t - off] : 0;
        __syncthreads(); s[t] += u; __syncthreads();
    }
    if (t < NBKT) { int ex = s[t] - v2; bktoff[t] = ex; bktcur[t] = ex; }
    if (t == NBKT - 1) bktoff[NBKT] = s[t];
    if (t == 0) dst_off[N_NODES] = N_EDGES;
}

// ---------------- kC: rel-scatter + dst-bucket scatter (LDS-aggregated) -----
__global__ __launch_bounds__(256) void kC_scatter(const int* __restrict__ src,
                                                  const int* __restrict__ dst,
                                                  const int* __restrict__ et,
                                                  int* __restrict__ relcur,
                                                  int* __restrict__ bktcur,
                                                  int* __restrict__ relsrc,
                                                  int* __restrict__ bucketed)
{
    __shared__ int lh[N_RELS],  lbase[N_RELS];
    __shared__ int lb[NBKT],    lbase2[NBKT];
    const int t = threadIdx.x;
    if (t < N_RELS) lh[t] = 0;
    if (t < NBKT)   lb[t] = 0;
    __syncthreads();
    const int base = blockIdx.x * EPB + t * 8;
    int r_[8], b_[8], s_[8], d_[8], sl[8], sl2[8];
    #pragma unroll
    for (int i = 0; i < 8; ++i) {
        int e = base + i;
        if (e < N_EDGES) {
            r_[i] = et[e]; s_[i] = src[e]; d_[i] = dst[e];
            b_[i] = d_[i] >> 8;
            sl[i]  = atomicAdd(&lh[r_[i]], 1);
            sl2[i] = atomicAdd(&lb[b_[i]], 1);
        }
    }
    __syncthreads();
    if (t < N_RELS && lh[t]) lbase[t]  = atomicAdd(&relcur[t], lh[t]);
    if (t < NBKT   && lb[t]) lbase2[t] = atomicAdd(&bktcur[t], lb[t]);
    __syncthreads();
    #pragma unroll
    for (int i = 0; i < 8; ++i) {
        int e = base + i;
        if (e < N_EDGES) {
            int j = lbase[r_[i]] + sl[i];
            relsrc[j] = s_[i];
            bucketed[lbase2[b_[i]] + sl2[i]] = ((d_[i] & 255) << 20) | j;
        }
    }
}

// ---------------- kD: per-bucket counting sort -> dst_off + j2pos -----------
__global__ __launch_bounds__(256) void kD_csr(const int* __restrict__ bucketed,
                                              const int* __restrict__ bktoff,
                                              int* __restrict__ j2pos,
                                              int* __restrict__ dst_off)
{
    __shared__ int hist[256];
    __shared__ int s[256];
    const int b = blockIdx.x, t = threadIdx.x;
    const int lo = bktoff[b], hi = bktoff[b + 1];
    hist[t] = 0; __syncthreads();
    for (int p = lo + t; p < hi; p += 256)
        atomicAdd(&hist[bucketed[p] >> 20], 1);
    __syncthreads();
    int v = hist[t];
    s[t] = v; __syncthreads();
    #pragma unroll
    for (int off = 1; off < 256; off <<= 1) {
        int u = (t >= off) ? s[t - off] : 0;
        __syncthreads(); s[t] += u; __syncthreads();
    }
    int ex = lo + s[t] - v;
    int n = b * 256 + t;
    if (n < N_NODES) dst_off[n] = ex;
    hist[t] = ex;
    __syncthreads();
    for (int p = lo + t; p < hi; p += 256) {
        int key = bucketed[p];
        int pos = atomicAdd(&hist[key >> 20], 1);
        j2pos[key & 0xFFFFF] = pos;        // inverse map: rel-index -> dst-CSR slot
    }
}

// ---------------- K4: per-relation GEMM via MFMA -> Y (dst-ordered) ---------
// TILE_M=128, 256 threads (4 waves). A-fragments loaded DIRECTLY from global
// (per-lane 2x16B slices of the gathered row — no reuse, so no LDS staging).
// Only W^T (reused by all 128 rows) + ypos live in LDS (~8.7 KB).
template <bool USE_H>
__global__ __launch_bounds__(256) void k4_gemm(const float* __restrict__ feat,
                                               const _Float16* __restrict__ featH,
                                               const _Float16* __restrict__ wT,
                                               const int* __restrict__ relsrc,
                                               const int* __restrict__ j2pos,
                                               const int* __restrict__ roff,
                                               const int* __restrict__ tb,
                                               _Float16* __restrict__ Y)
{
    __shared__ _Float16 wL[64 * 64];       // XOR-swizzled [out][k], 8 KB
    __shared__ int      ypos[TILE_M];      // dst-CSR slot per tile row
    const int b = blockIdx.x, t = threadIdx.x;

    int r = -1, ti = 0, t0 = 0;
    #pragma unroll
    for (int q = 0; q < N_RELS; ++q) {
        int t1 = tb[q + 1];
        if (b >= t0 && b < t1) { r = q; ti = b - t0; }
        t0 = t1;
    }
    if (r < 0) return;
    const int segend  = roff[r + 1];
    const int rowbase = roff[r] + ti * TILE_M;

    if (t < TILE_M) {
        const int j = rowbase + t;
        ypos[t] = (j < segend) ? j2pos[j] : 0;
    } else {
        const _Float16* wsrc = wT + (size_t)r * 4096;
        const int tt = t - 128;
        #pragma unroll
        for (int it = 0; it < 4; ++it) {
            int L8 = it * 128 + tt;
            int o = L8 >> 3, kcol = (L8 & 7) * 8;
            int baddr = (o * 128 + kcol * 2) ^ ((o & 7) << 4);
            *reinterpret_cast<half8*>(reinterpret_cast<char*>(wL) + baddr) =
                *reinterpret_cast<const half8*>(wsrc + L8 * 8);
        }
    }

    const int wid = t >> 6, l = t & 63;
    const int lrow = l & 15, lkb = l >> 4;

    // direct A-fragment gather (overlaps with W staging; no dependency on LDS)
    half8 af[2][2];                        // [rt][ks]
    #pragma unroll
    for (int rt = 0; rt < 2; ++rt) {
        const int row = wid * 32 + rt * 16 + lrow;
        const int j = rowbase + row;
        const int sidx = (j < segend) ? relsrc[j] : 0;
        if (USE_H) {
            const _Float16* ar = featH + ((size_t)sidx << 6) + lkb * 8;
            af[rt][0] = *reinterpret_cast<const half8*>(ar);
            af[rt][1] = *reinterpret_cast<const half8*>(ar + 32);
        } else {
            const float* ar = feat + ((size_t)sidx << 6) + lkb * 8;
            float4 a0 = *reinterpret_cast<const float4*>(ar);
            float4 a1 = *reinterpret_cast<const float4*>(ar + 4);
            float4 a2 = *reinterpret_cast<const float4*>(ar + 32);
            float4 a3 = *reinterpret_cast<const float4*>(ar + 36);
            half8 h0, h1;
            h0[0]=(_Float16)a0.x; h0[1]=(_Float16)a0.y; h0[2]=(_Float16)a0.z; h0[3]=(_Float16)a0.w;
            h0[4]=(_Float16)a1.x; h0[5]=(_Float16)a1.y; h0[6]=(_Float16)a1.z; h0[7]=(_Float16)a1.w;
            h1[0]=(_Float16)a2.x; h1[1]=(_Float16)a2.y; h1[2]=(_Float16)a2.z; h1[3]=(_Float16)a2.w;
            h1[4]=(_Float16)a3.x; h1[5]=(_Float16)a3.y; h1[6]=(_Float16)a3.z; h1[7]=(_Float16)a3.w;
            af[rt][0] = h0; af[rt][1] = h1;
        }
    }
    __syncthreads();

    f32x4 acc[2][4] = {};
    #pragma unroll
    for (int ks = 0; ks < 2; ++ks) {
        half8 bfr[4];
        #pragma unroll
        for (int ct = 0; ct < 4; ++ct) {
            int n = ct * 16 + lrow;
            int baddr = (n * 128 + ks * 64 + lkb * 16) ^ ((n & 7) << 4);
            bfr[ct] = *reinterpret_cast<const half8*>(reinterpret_cast<const char*>(wL) + baddr);
        }
        #pragma unroll
        for (int rt = 0; rt < 2; ++rt)
            #pragma unroll
            for (int ct = 0; ct < 4; ++ct)
                acc[rt][ct] = __builtin_amdgcn_mfma_f32_16x16x32_f16(af[rt][ks], bfr[ct], acc[rt][ct], 0, 0, 0);
    }
    #pragma unroll
    for (int rt = 0; rt < 2; ++rt) {
        int lrow0 = wid * 32 + rt * 16 + (l >> 4) * 4;
        #pragma unroll
        for (int reg = 0; reg < 4; ++reg) {
            int lr = lrow0 + reg;
            if (rowbase + lr < segend) {
                size_t yrow = (size_t)ypos[lr] * 64;
                #pragma unroll
                for (int ct = 0; ct < 4; ++ct)
                    Y[yrow + ct * 16 + lrow] = (_Float16)acc[rt][ct][reg];
            }
        }
    }
}

// ---------------- K5: vectorized streaming reduce over dst-ordered Y --------
__global__ __launch_bounds__(256) void k5_reduce(const _Float16* __restrict__ Y,
                                                 const int* __restrict__ dst_off,
                                                 float* __restrict__ out)
{
    const int wid = threadIdx.x >> 6, l = threadIdx.x & 63;
    const int n = blockIdx.x * 4 + wid;
    if (n >= N_NODES) return;
    const int p0 = dst_off[n], p1 = dst_off[n + 1];
    const int rg = l >> 3;     // row group 0..7
    const int cg = l & 7;      // col group 0..7 (8 cols each)
    float a[8] = {0,0,0,0,0,0,0,0};
    for (int p = p0; p < p1; p += 8) {
        int row = p + rg;
        if (row < p1) {
            half8 v = *reinterpret_cast<const half8*>(Y + (size_t)row * 64 + cg * 8);
            #pragma unroll
            for (int i = 0; i < 8; ++i) a[i] += (float)v[i];
        }
    }
    #pragma unroll
    for (int m = 8; m < 64; m <<= 1)
        #pragma unroll
        for (int i = 0; i < 8; ++i)
            a[i] += __shfl_xor(a[i], m, 64);
    if (rg == 0) {
        float* orow = out + (size_t)n * 64 + cg * 8;
        f32x4 v0 = {a[0], a[1], a[2], a[3]};
        f32x4 v1 = {a[4], a[5], a[6], a[7]};
        *reinterpret_cast<f32x4*>(orow)     = v0;
        *reinterpret_cast<f32x4*>(orow + 4) = v1;
    }
}

extern "C" void kernel_launch(void* const* d_in, const int* in_sizes, int n_in,
                              void* d_out, int out_size, void* d_ws, size_t ws_size,
                              hipStream_t stream) {
    const float* feat   = (const float*)d_in[0];
    const float* weight = (const float*)d_in[1];
    const int*   src    = (const int*)d_in[2];
    const int*   dst    = (const int*)d_in[3];
    const int*   et     = (const int*)d_in[4];
    float*       out    = (float*)d_out;

    if (ws_size < (size_t)WS_BASE) {
        hipMemsetAsync(d_out, 0, (size_t)out_size * sizeof(float), stream);
        hipLaunchKernelGGL(rgcn_edge_atomic, dim3(4096), dim3(256), 0, stream,
                           feat, weight, src, dst, et, out, N_EDGES / 4);
        return;
    }
    const bool use_h = (ws_size >= (size_t)WS_FULL);

    char* ws = (char*)d_ws;
    int*       relhist  = (int*)(ws + OFF_RELHIST);
    int*       bkthist  = (int*)(ws + OFF_BKTHIST);
    int*       relcur   = (int*)(ws + OFF_RELCUR);
    int*       bktcur   = (int*)(ws + OFF_BKTCUR);
    int*       roff     = (int*)(ws + OFF_ROFF);
    int*       tb       = (int*)(ws + OFF_TB);
    int*       bktoff   = (int*)(ws + OFF_BKTOFF);
    int*       dst_off  = (int*)(ws + OFF_DSTOFF);
    int*       relsrc   = (int*)(ws + OFF_RELSRC);
    int*       j2pos    = (int*)(ws + OFF_J2POS);
    _Float16*  wT       = (_Float16*)(ws + OFF_WT);
    _Float16*  featH    = (_Float16*)(ws + OFF_FEATH);
    _Float16*  Y        = (_Float16*)(ws + (use_h ? OFF_Y_FULL : OFF_Y_BASE));
    int*       bucketed = (int*)Y;              // aliases Y head; dead before k4

    const int pre_blocks = use_h ? (N_RELS + (N_NODES * D / 8 + 255) / 256) : N_RELS;
    hipLaunchKernelGGL(kPre,       dim3(pre_blocks), dim3(256), 0, stream, weight, wT, feat, featH, (int*)ws);
    hipLaunchKernelGGL(kA_hist,    dim3(NEBLK),  dim3(256), 0, stream, et, dst, relhist, bkthist);
    hipLaunchKernelGGL(kB_scan,    dim3(1),      dim3(256), 0, stream, relhist, bkthist, roff, relcur, tb, bktoff, bktcur, dst_off);
    hipLaunchKernelGGL(kC_scatter, dim3(NEBLK),  dim3(256), 0, stream, src, dst, et, relcur, bktcur, relsrc, bucketed);
    hipLaunchKernelGGL(kD_csr,     dim3(NBKT),   dim3(256), 0, stream, bucketed, bktoff, j2pos, dst_off);
    const int max_tiles = N_EDGES / TILE_M + N_RELS;   // 6282 upper bound
    if (use_h)
        hipLaunchKernelGGL((k4_gemm<true>),  dim3(max_tiles), dim3(256), 0, stream, feat, featH, wT, relsrc, j2pos, roff, tb, Y);
    else
        hipLaunchKernelGGL((k4_gemm<false>), dim3(max_tiles), dim3(256), 0, stream, feat, featH, wT, relsrc, j2pos, roff, tb, Y);
    hipLaunchKernelGGL(k5_reduce,  dim3((N_NODES + 3) / 4), dim3(256), 0, stream, Y, dst_off, out);
}

// Round 13
// 108.126 us; speedup vs baseline: 4.3553x; 1.0236x over previous
//
#include <hip/hip_runtime.h>
#include <hip/hip_bf16.h>

#define N_NODES 50000
#define N_EDGES 800000
#define N_RELS  32
#define D       64
#define TILE_M  128
#define NBKT    196                         // ceil(50000/256) dst buckets
#define EPB     2048                        // edges per block in kC
#define NEBLK   ((N_EDGES + EPB - 1) / EPB) // 391
#define SEGCAP  27008                       // per-rel fixed cap (211*128; mean 25000, +12.9σ)
#define CAPB    4608                        // per-bucket fixed cap (mean 4082, +8.2σ)
#define NT_MAX  (N_RELS * (SEGCAP / TILE_M))// 6752 tile upper bound
#define FEATH_BLKS ((N_NODES * D / 8 + 255) / 256)   // 1563

typedef _Float16 half8 __attribute__((ext_vector_type(8)));
typedef float    f32x4 __attribute__((ext_vector_type(4)));

// ---------------- workspace layout (bytes) ----------------
#define OFF_RELCUR  0u          // 32 int  (init to r*SEGCAP by kPre)
#define OFF_BKTCUR  128u        // 196 int (init to b*CAPB by kPre)
#define OFF_TB      912u        // 33 int  (pad to 1056 after)
#define OFF_DSTOFF  1056u       // 50000 int
#define OFF_RELSRC  201056u     // 864256 int (32 segments x 27008)
#define OFF_J2POS   3658080u    // 864256 int
#define OFF_BUCK    7115104u    // 903168 int (196 x 4608)
#define OFF_WT      10727776u   // 32*64*64 fp16
#define OFF_FEATH   10989920u   // 50000*64 fp16 (full tier only)
#define OFF_Y_FULL  17389920u   // 903168*64 fp16
#define OFF_Y_BASE  10989920u   // Y when featH doesn't fit
#define WS_H        132995424u
#define WS_B        126595424u

// ---------------- fallback: atomic scatter path ----------------
__global__ __launch_bounds__(256) void rgcn_edge_atomic(
    const float* __restrict__ feat, const float* __restrict__ weight,
    const int* __restrict__ src, const int* __restrict__ dst,
    const int* __restrict__ et, float* __restrict__ out, int nquads)
{
    const int tid  = blockIdx.x * blockDim.x + threadIdx.x;
    const int wave = tid >> 6, lane = tid & 63;
    const int grp = lane >> 4, lg = lane & 15;
    const int wave_stride = (gridDim.x * blockDim.x) >> 6;
    for (int q = wave; q < nquads; q += wave_stride) {
        const int e = q * 4 + grp;
        const int s = src[e], d = dst[e], r = et[e];
        const float* w = weight + (size_t)r * D * D + lg * 4;
        float ax = 0.f, ay = 0.f, az = 0.f, aw = 0.f;
        #pragma unroll
        for (int i4 = 0; i4 < D / 4; ++i4) {
            const float4 f  = *reinterpret_cast<const float4*>(feat + (size_t)s * D + i4 * 4);
            const float4 w0 = *reinterpret_cast<const float4*>(w + (i4 * 4 + 0) * D);
            const float4 w1 = *reinterpret_cast<const float4*>(w + (i4 * 4 + 1) * D);
            const float4 w2 = *reinterpret_cast<const float4*>(w + (i4 * 4 + 2) * D);
            const float4 w3 = *reinterpret_cast<const float4*>(w + (i4 * 4 + 3) * D);
            ax += f.x*w0.x; ay += f.x*w0.y; az += f.x*w0.z; aw += f.x*w0.w;
            ax += f.y*w1.x; ay += f.y*w1.y; az += f.y*w1.z; aw += f.y*w1.w;
            ax += f.z*w2.x; ay += f.z*w2.y; az += f.z*w2.z; aw += f.z*w2.w;
            ax += f.w*w3.x; ay += f.w*w3.y; az += f.w*w3.z; aw += f.w*w3.w;
        }
        float* orow = out + (size_t)d * D + lg * 4;
        atomicAdd(orow + 0, ax); atomicAdd(orow + 1, ay);
        atomicAdd(orow + 2, az); atomicAdd(orow + 3, aw);
    }
}

// ---------------- kPre: init cursors + W->W^T fp16 + feat->fp16 -------------
__global__ __launch_bounds__(256) void kPre(const float* __restrict__ w,
                                            _Float16* __restrict__ wT,
                                            const float* __restrict__ feat,
                                            _Float16* __restrict__ featH,
                                            int* __restrict__ relcur,
                                            int* __restrict__ bktcur)
{
    const int t = threadIdx.x;
    if (blockIdx.x < N_RELS) {
        if (blockIdx.x == 0) {
            if (t < N_RELS)                relcur[t] = t * SEGCAP;
            else if (t < N_RELS + NBKT)    bktcur[t - N_RELS] = (t - N_RELS) * CAPB;
        }
        const int r = blockIdx.x;
        #pragma unroll
        for (int i = 0; i < 16; ++i) {
            int oidx = i * 256 + t;
            int o = oidx >> 6, k = oidx & 63;
            wT[(size_t)r * 4096 + oidx] = (_Float16)w[(size_t)r * 4096 + k * 64 + o];
        }
    } else {
        const int base = ((blockIdx.x - N_RELS) * 256 + t) * 8;
        if (base >= N_NODES * D) return;
        float4 f0 = *reinterpret_cast<const float4*>(feat + base);
        float4 f1 = *reinterpret_cast<const float4*>(feat + base + 4);
        half8 h;
        h[0]=(_Float16)f0.x; h[1]=(_Float16)f0.y; h[2]=(_Float16)f0.z; h[3]=(_Float16)f0.w;
        h[4]=(_Float16)f1.x; h[5]=(_Float16)f1.y; h[6]=(_Float16)f1.z; h[7]=(_Float16)f1.w;
        *reinterpret_cast<half8*>(featH + base) = h;
    }
}

// ---------------- kC: rel-scatter + dst-bucket scatter (fixed-cap bases) ----
__global__ __launch_bounds__(256) void kC_scatter(const int* __restrict__ src,
                                                  const int* __restrict__ dst,
                                                  const int* __restrict__ et,
                                                  int* __restrict__ relcur,
                                                  int* __restrict__ bktcur,
                                                  int* __restrict__ relsrc,
                                                  int* __restrict__ bucketed)
{
    __shared__ int lh[N_RELS],  lbase[N_RELS];
    __shared__ int lb[NBKT],    lbase2[NBKT];
    const int t = threadIdx.x;
    if (t < N_RELS) lh[t] = 0;
    if (t < NBKT)   lb[t] = 0;
    __syncthreads();
    const int base = blockIdx.x * EPB + t * 8;
    int r_[8], b_[8], s_[8], d_[8], sl[8], sl2[8];
    #pragma unroll
    for (int i = 0; i < 8; ++i) {
        int e = base + i;
        if (e < N_EDGES) {
            r_[i] = et[e]; s_[i] = src[e]; d_[i] = dst[e];
            b_[i] = d_[i] >> 8;
            sl[i]  = atomicAdd(&lh[r_[i]], 1);
            sl2[i] = atomicAdd(&lb[b_[i]], 1);
        }
    }
    __syncthreads();
    if (t < N_RELS && lh[t]) lbase[t]  = atomicAdd(&relcur[t], lh[t]);
    if (t < NBKT   && lb[t]) lbase2[t] = atomicAdd(&bktcur[t], lb[t]);
    __syncthreads();
    #pragma unroll
    for (int i = 0; i < 8; ++i) {
        int e = base + i;
        if (e < N_EDGES) {
            int j    = lbase[r_[i]] + sl[i];
            int pos2 = lbase2[b_[i]] + sl2[i];
            if (j < N_RELS * SEGCAP) relsrc[j] = s_[i];            // cap guard (~13σ)
            if (pos2 < NBKT * CAPB)
                bucketed[pos2] = ((d_[i] & 255) << 20) | j;
        }
    }
}

// ---------------- kD': per-bucket counting sort + (block NBKT) tile scan ----
__global__ __launch_bounds__(256) void kD_csr(const int* __restrict__ bucketed,
                                              const int* __restrict__ bktcur,
                                              const int* __restrict__ relcur,
                                              int* __restrict__ j2pos,
                                              int* __restrict__ dst_off,
                                              int* __restrict__ tb)
{
    __shared__ int hist[256];
    __shared__ int s[256];
    const int b = blockIdx.x, t = threadIdx.x;
    if (b == NBKT) {
        // tile-table scan from final rel cursors
        int c = 0, w = 0;
        if (t < N_RELS) {
            c = min(relcur[t] - t * SEGCAP, SEGCAP);
            w = (c + TILE_M - 1) >> 7;
        }
        s[t] = (t < N_RELS) ? w : 0; __syncthreads();
        #pragma unroll
        for (int off = 1; off < N_RELS; off <<= 1) {
            int u = (t >= off && t < N_RELS) ? s[t - off] : 0;
            __syncthreads(); s[t] += u; __syncthreads();
        }
        if (t < N_RELS) tb[t] = s[t] - w;
        if (t == N_RELS - 1) tb[N_RELS] = s[t];
        return;
    }
    const int lo = b * CAPB;
    const int hi = min(bktcur[b], lo + CAPB);
    hist[t] = 0; __syncthreads();
    for (int p = lo + t; p < hi; p += 256)
        atomicAdd(&hist[bucketed[p] >> 20], 1);
    __syncthreads();
    int v = hist[t];
    s[t] = v; __syncthreads();
    #pragma unroll
    for (int off = 1; off < 256; off <<= 1) {
        int u = (t >= off) ? s[t - off] : 0;
        __syncthreads(); s[t] += u; __syncthreads();
    }
    int ex = lo + s[t] - v;
    int n = b * 256 + t;
    if (n < N_NODES) dst_off[n] = ex;
    hist[t] = ex;
    __syncthreads();
    for (int p = lo + t; p < hi; p += 256) {
        int key = bucketed[p];
        int pos = atomicAdd(&hist[key >> 20], 1);
        j2pos[key & 0xFFFFF] = pos;        // rel-index j -> dst-CSR slot
    }
}

// ---------------- K4: per-relation GEMM via MFMA -> Y (dst-ordered) ---------
// TILE_M=128, 4 waves. Direct-from-global A fragments; W^T + ypos in LDS.
template <bool USE_H>
__global__ __launch_bounds__(256) void k4_gemm(const float* __restrict__ feat,
                                               const _Float16* __restrict__ featH,
                                               const _Float16* __restrict__ wT,
                                               const int* __restrict__ relsrc,
                                               const int* __restrict__ j2pos,
                                               const int* __restrict__ relcur,
                                               const int* __restrict__ tb,
                                               _Float16* __restrict__ Y)
{
    __shared__ _Float16 wL[64 * 64];       // XOR-swizzled [out][k], 8 KB
    __shared__ int      ypos[TILE_M];
    const int b = blockIdx.x, t = threadIdx.x;

    int r = -1, ti = 0, t0 = 0;
    #pragma unroll
    for (int q = 0; q < N_RELS; ++q) {
        int t1 = tb[q + 1];
        if (b >= t0 && b < t1) { r = q; ti = b - t0; }
        t0 = t1;
    }
    if (r < 0) return;
    const int segend  = min(relcur[r], (r + 1) * SEGCAP);
    const int rowbase = r * SEGCAP + ti * TILE_M;

    if (t < TILE_M) {
        const int j = rowbase + t;
        ypos[t] = (j < segend) ? j2pos[j] : 0;
    } else {
        const _Float16* wsrc = wT + (size_t)r * 4096;
        const int tt = t - 128;
        #pragma unroll
        for (int it = 0; it < 4; ++it) {
            int L8 = it * 128 + tt;
            int o = L8 >> 3, kcol = (L8 & 7) * 8;
            int baddr = (o * 128 + kcol * 2) ^ ((o & 7) << 4);
            *reinterpret_cast<half8*>(reinterpret_cast<char*>(wL) + baddr) =
                *reinterpret_cast<const half8*>(wsrc + L8 * 8);
        }
    }

    const int wid = t >> 6, l = t & 63;
    const int lrow = l & 15, lkb = l >> 4;

    half8 af[2][2];                        // [rt][ks]
    #pragma unroll
    for (int rt = 0; rt < 2; ++rt) {
        const int row = wid * 32 + rt * 16 + lrow;
        const int j = rowbase + row;
        const int sidx = (j < segend) ? relsrc[j] : 0;
        if (USE_H) {
            const _Float16* ar = featH + ((size_t)sidx << 6) + lkb * 8;
            af[rt][0] = *reinterpret_cast<const half8*>(ar);
            af[rt][1] = *reinterpret_cast<const half8*>(ar + 32);
        } else {
            const float* ar = feat + ((size_t)sidx << 6) + lkb * 8;
            float4 a0 = *reinterpret_cast<const float4*>(ar);
            float4 a1 = *reinterpret_cast<const float4*>(ar + 4);
            float4 a2 = *reinterpret_cast<const float4*>(ar + 32);
            float4 a3 = *reinterpret_cast<const float4*>(ar + 36);
            half8 h0, h1;
            h0[0]=(_Float16)a0.x; h0[1]=(_Float16)a0.y; h0[2]=(_Float16)a0.z; h0[3]=(_Float16)a0.w;
            h0[4]=(_Float16)a1.x; h0[5]=(_Float16)a1.y; h0[6]=(_Float16)a1.z; h0[7]=(_Float16)a1.w;
            h1[0]=(_Float16)a2.x; h1[1]=(_Float16)a2.y; h1[2]=(_Float16)a2.z; h1[3]=(_Float16)a2.w;
            h1[4]=(_Float16)a3.x; h1[5]=(_Float16)a3.y; h1[6]=(_Float16)a3.z; h1[7]=(_Float16)a3.w;
            af[rt][0] = h0; af[rt][1] = h1;
        }
    }
    __syncthreads();

    f32x4 acc[2][4] = {};
    #pragma unroll
    for (int ks = 0; ks < 2; ++ks) {
        half8 bfr[4];
        #pragma unroll
        for (int ct = 0; ct < 4; ++ct) {
            int n = ct * 16 + lrow;
            int baddr = (n * 128 + ks * 64 + lkb * 16) ^ ((n & 7) << 4);
            bfr[ct] = *reinterpret_cast<const half8*>(reinterpret_cast<const char*>(wL) + baddr);
        }
        #pragma unroll
        for (int rt = 0; rt < 2; ++rt)
            #pragma unroll
            for (int ct = 0; ct < 4; ++ct)
                acc[rt][ct] = __builtin_amdgcn_mfma_f32_16x16x32_f16(af[rt][ks], bfr[ct], acc[rt][ct], 0, 0, 0);
    }
    #pragma unroll
    for (int rt = 0; rt < 2; ++rt) {
        int lrow0 = wid * 32 + rt * 16 + (l >> 4) * 4;
        #pragma unroll
        for (int reg = 0; reg < 4; ++reg) {
            int lr = lrow0 + reg;
            if (rowbase + lr < segend) {
                size_t yrow = (size_t)ypos[lr] * 64;
                #pragma unroll
                for (int ct = 0; ct < 4; ++ct)
                    Y[yrow + ct * 16 + lrow] = (_Float16)acc[rt][ct][reg];
            }
        }
    }
}

// ---------------- K5: vectorized streaming reduce over dst-ordered Y --------
__global__ __launch_bounds__(256) void k5_reduce(const _Float16* __restrict__ Y,
                                                 const int* __restrict__ dst_off,
                                                 const int* __restrict__ bktcur,
                                                 float* __restrict__ out)
{
    const int wid = threadIdx.x >> 6, l = threadIdx.x & 63;
    const int n = blockIdx.x * 4 + wid;
    if (n >= N_NODES) return;
    const int b = n >> 8;
    const int p0 = dst_off[n];
    int p1 = ((n & 255) == 255 || n == N_NODES - 1) ? bktcur[b] : dst_off[n + 1];
    p1 = min(p1, (b + 1) * CAPB);
    const int rg = l >> 3;
    const int cg = l & 7;
    float a[8] = {0,0,0,0,0,0,0,0};
    for (int p = p0; p < p1; p += 8) {
        int row = p + rg;
        if (row < p1) {
            half8 v = *reinterpret_cast<const half8*>(Y + (size_t)row * 64 + cg * 8);
            #pragma unroll
            for (int i = 0; i < 8; ++i) a[i] += (float)v[i];
        }
    }
    #pragma unroll
    for (int m = 8; m < 64; m <<= 1)
        #pragma unroll
        for (int i = 0; i < 8; ++i)
            a[i] += __shfl_xor(a[i], m, 64);
    if (rg == 0) {
        float* orow = out + (size_t)n * 64 + cg * 8;
        f32x4 v0 = {a[0], a[1], a[2], a[3]};
        f32x4 v1 = {a[4], a[5], a[6], a[7]};
        *reinterpret_cast<f32x4*>(orow)     = v0;
        *reinterpret_cast<f32x4*>(orow + 4) = v1;
    }
}

extern "C" void kernel_launch(void* const* d_in, const int* in_sizes, int n_in,
                              void* d_out, int out_size, void* d_ws, size_t ws_size,
                              hipStream_t stream) {
    const float* feat   = (const float*)d_in[0];
    const float* weight = (const float*)d_in[1];
    const int*   src    = (const int*)d_in[2];
    const int*   dst    = (const int*)d_in[3];
    const int*   et     = (const int*)d_in[4];
    float*       out    = (float*)d_out;

    if (ws_size < (size_t)WS_B) {
        hipMemsetAsync(d_out, 0, (size_t)out_size * sizeof(float), stream);
        hipLaunchKernelGGL(rgcn_edge_atomic, dim3(4096), dim3(256), 0, stream,
                           feat, weight, src, dst, et, out, N_EDGES / 4);
        return;
    }
    const bool use_h = (ws_size >= (size_t)WS_H);

    char* ws = (char*)d_ws;
    int*       relcur   = (int*)(ws + OFF_RELCUR);
    int*       bktcur   = (int*)(ws + OFF_BKTCUR);
    int*       tb       = (int*)(ws + OFF_TB);
    int*       dst_off  = (int*)(ws + OFF_DSTOFF);
    int*       relsrc   = (int*)(ws + OFF_RELSRC);
    int*       j2pos    = (int*)(ws + OFF_J2POS);
    int*       bucketed = (int*)(ws + OFF_BUCK);
    _Float16*  wT       = (_Float16*)(ws + OFF_WT);
    _Float16*  featH    = (_Float16*)(ws + OFF_FEATH);
    _Float16*  Y        = (_Float16*)(ws + (use_h ? OFF_Y_FULL : OFF_Y_BASE));

    const int pre_blocks = N_RELS + (use_h ? FEATH_BLKS : 0);
    hipLaunchKernelGGL(kPre,       dim3(pre_blocks), dim3(256), 0, stream,
                       weight, wT, feat, featH, relcur, bktcur);
    hipLaunchKernelGGL(kC_scatter, dim3(NEBLK),    dim3(256), 0, stream,
                       src, dst, et, relcur, bktcur, relsrc, bucketed);
    hipLaunchKernelGGL(kD_csr,     dim3(NBKT + 1), dim3(256), 0, stream,
                       bucketed, bktcur, relcur, j2pos, dst_off, tb);
    if (use_h)
        hipLaunchKernelGGL((k4_gemm<true>),  dim3(NT_MAX), dim3(256), 0, stream,
                           feat, featH, wT, relsrc, j2pos, relcur, tb, Y);
    else
        hipLaunchKernelGGL((k4_gemm<false>), dim3(NT_MAX), dim3(256), 0, stream,
                           feat, featH, wT, relsrc, j2pos, relcur, tb, Y);
    hipLaunchKernelGGL(k5_reduce,  dim3((N_NODES + 3) / 4), dim3(256), 0, stream,
                       Y, dst_off, bktcur, out);
}